// Round 15
// baseline (515.550 us; speedup 1.0000x reference)
//
#include <hip/hip_runtime.h>

#define HSZ 64
#define ISZ 8
#define TSZ 512
#define BTILE 16   // batch rows per block
#define NW 16      // waves per block (1024 threads) -> 4 waves/SIMD
#define KP 72      // u16 per row: [0,64) h + 8 pad; 144 B row stride

typedef _Float16 f16;
typedef __attribute__((ext_vector_type(8))) _Float16 f16x8;
typedef __attribute__((ext_vector_type(4))) float f32x4;
typedef unsigned short u16;

__device__ __forceinline__ u16 f16bits(float f) {
    union { f16 h; u16 u; } v; v.h = (f16)f;
    return v.u;
}

// r9 structure (best measured: 254us) with ONE change: x never touches LDS.
// Operand-swapped MFMA: A = weights (M = 16 gate rows, gc = gate*64+4w+(lr>>2)),
// B = h (LDS) / x (registers), N = 16 batch. Lane (lr,lg) holds all 4 gates of
// unit (batch lr, hidden 4w+lg) in acc[0..3] -> act fully lane-local.
// Bias = MFMA C-in, pre-scaled by -log2e / -2log2e (act uses exp2 directly).
// x: each lane loads batch row lr from global (dup lanes L1-broadcast),
// converts to f16x8 b2; wa2 is zero for lg>=1 so garbage B-slices contribute
// exactly 0. Cuts LDS traffic per CU-step from 48 to 32 ds_read_b128 and
// deletes the x-staging writes. Plain __syncthreads (r14's asm barrier +
// sched_barrier defeated compiler pipelining: 454us).
__global__ __launch_bounds__(1024, 4) void lstm_w16d(
    const float* __restrict__ x,      // [B, T, I]
    const float* __restrict__ W_ih,   // [4H, I]
    const float* __restrict__ W_hh,   // [4H, H]
    const float* __restrict__ b_ih,   // [4H]
    const float* __restrict__ b_hh,   // [4H]
    const float* __restrict__ W_fc,   // [O, H]
    const float* __restrict__ b_fc,   // [O]
    float* __restrict__ out)          // [B, O]
{
    const int tid = threadIdx.x;
    const int w  = tid >> 6;          // wave 0..15, owns hidden units [4w, 4w+4)
    const int l  = tid & 63;
    const int lr = l & 15;            // A: M-row sel / B,C: batch col
    const int lg = l >> 4;            // k-group; act: hidden unit 4w+lg
    const int B0 = blockIdx.x * BTILE;
    const int hcol = 4 * w + lg;      // this lane's hidden unit

    __shared__ __align__(16) u16 H[2][BTILE][KP];  // [buf][batch row][k(h)]
    __shared__ float red[NW][BTILE];

    for (int i = tid; i < 2 * BTILE * KP; i += 1024)
        ((u16*)H)[i] = 0;

    // ---- A-fragments (weights), pre-scaled; bias as C-in ----
    const int gate = lr & 3;
    const int gc   = gate * HSZ + 4 * w + (lr >> 2);   // gate row in [0,256)
    const float sc = (gate == 2) ? -2.885390082f : -1.442695041f;
    f16x8 wa0, wa1, wa2;
    {
        const float4 a = *reinterpret_cast<const float4*>(&W_hh[gc * HSZ + lg * 8]);
        const float4 b = *reinterpret_cast<const float4*>(&W_hh[gc * HSZ + lg * 8 + 4]);
        wa0[0] = (f16)(sc * a.x); wa0[1] = (f16)(sc * a.y);
        wa0[2] = (f16)(sc * a.z); wa0[3] = (f16)(sc * a.w);
        wa0[4] = (f16)(sc * b.x); wa0[5] = (f16)(sc * b.y);
        wa0[6] = (f16)(sc * b.z); wa0[7] = (f16)(sc * b.w);
    }
    {
        const float4 a = *reinterpret_cast<const float4*>(&W_hh[gc * HSZ + 32 + lg * 8]);
        const float4 b = *reinterpret_cast<const float4*>(&W_hh[gc * HSZ + 32 + lg * 8 + 4]);
        wa1[0] = (f16)(sc * a.x); wa1[1] = (f16)(sc * a.y);
        wa1[2] = (f16)(sc * a.z); wa1[3] = (f16)(sc * a.w);
        wa1[4] = (f16)(sc * b.x); wa1[5] = (f16)(sc * b.y);
        wa1[6] = (f16)(sc * b.z); wa1[7] = (f16)(sc * b.w);
    }
#pragma unroll
    for (int j = 0; j < 8; ++j) wa2[j] = (f16)0.0f;
    if (lg == 0) {                    // x-MFMA k-slice [0,8) = W_ih; rest zero
        const float4 a = *reinterpret_cast<const float4*>(&W_ih[gc * ISZ]);
        const float4 b = *reinterpret_cast<const float4*>(&W_ih[gc * ISZ + 4]);
        wa2[0] = (f16)(sc * a.x); wa2[1] = (f16)(sc * a.y);
        wa2[2] = (f16)(sc * a.z); wa2[3] = (f16)(sc * a.w);
        wa2[4] = (f16)(sc * b.x); wa2[5] = (f16)(sc * b.y);
        wa2[6] = (f16)(sc * b.z); wa2[7] = (f16)(sc * b.w);
    }

    // per-lane bias vector (C-in of the x-MFMA): gate r of unit hcol
    f32x4 bias4;
#pragma unroll
    for (int r = 0; r < 4; ++r) {
        const float s = (r == 2) ? -2.885390082f : -1.442695041f;
        bias4[r] = s * (b_ih[r * HSZ + hcol] + b_hh[r * HSZ + hcol]);
    }

    __syncthreads();  // zeroing visible (h(0)=0 in both buffers)

    // hoisted LDS offsets (u16 units)
    const u16* rd0 = &H[0][lr][lg * 8];
    const u16* rd1 = &H[1][lr][lg * 8];
    u16* wr0 = &H[0][lr][hcol];
    u16* wr1 = &H[1][lr][hcol];

    // x: every lane loads batch row lr (dup lanes -> L1 broadcast)
    const float* xrow = x + (size_t)(B0 + lr) * TSZ * ISZ;
    float4 xa = *reinterpret_cast<const float4*>(xrow);
    float4 xb = *reinterpret_cast<const float4*>(xrow + 4);

    float c = 0.0f, h = 0.0f;
    const float L2 = 2.885390082f;

#define STEP(RD, WR, T, GUARD)                                                 \
    {                                                                          \
        f16x8 b2;                                                              \
        b2[0] = (f16)xa.x; b2[1] = (f16)xa.y; b2[2] = (f16)xa.z;               \
        b2[3] = (f16)xa.w; b2[4] = (f16)xb.x; b2[5] = (f16)xb.y;               \
        b2[6] = (f16)xb.z; b2[7] = (f16)xb.w;                                  \
        if (GUARD) {  /* prefetch x(T+1): ~1 full step of latency cover */     \
            xa = *reinterpret_cast<const float4*>(xrow + (size_t)(T + 1) * ISZ);     \
            xb = *reinterpret_cast<const float4*>(xrow + (size_t)(T + 1) * ISZ + 4); \
        }                                                                      \
        const f16x8 b0 = *reinterpret_cast<const f16x8*>(RD);                  \
        const f16x8 b1 = *reinterpret_cast<const f16x8*>(RD + 32);             \
        f32x4 acc = __builtin_amdgcn_mfma_f32_16x16x32_f16(wa2, b2, bias4, 0, 0, 0); \
        acc = __builtin_amdgcn_mfma_f32_16x16x32_f16(wa0, b0, acc, 0, 0, 0);   \
        acc = __builtin_amdgcn_mfma_f32_16x16x32_f16(wa1, b1, acc, 0, 0, 0);   \
        const float ea = __builtin_amdgcn_exp2f(acc[0]);                       \
        const float eb = __builtin_amdgcn_exp2f(acc[1]);                       \
        const float ed = __builtin_amdgcn_exp2f(acc[2]);                       \
        const float es = __builtin_amdgcn_exp2f(acc[3]);                       \
        const float A1 = 1.0f + ea, B1 = 1.0f + eb, D1 = 1.0f + ed;            \
        const float R1 = __builtin_amdgcn_rcpf(A1 * B1 * D1);                  \
        c = fmaf(c * A1, D1, (1.0f - ed) * B1) * R1;                           \
        const float eu = __builtin_amdgcn_exp2f(-L2 * c);                      \
        const float R2 = __builtin_amdgcn_rcpf((1.0f + es) * (1.0f + eu));     \
        h = (1.0f - eu) * R2;                                                  \
        *(WR) = f16bits(h);                                                    \
        __syncthreads();                                                       \
    }

    for (int t = 0; t < TSZ; t += 2) {
        // step t: read buf0, write h into buf1. x(t+1) always exists (t+1<=511).
        STEP(rd0, wr1, t, true)
        // step t+1: read buf1, write into buf0. x(t+2) exists unless t == 510.
        STEP(rd1, wr0, t + 1, t < TSZ - 2)
    }
#undef STEP

    // ---- final FC: out[b] = sum_h h(b,hu) * W_fc[hu] + b_fc ----
    float v = h * W_fc[hcol];
    v += __shfl_xor(v, 16);
    v += __shfl_xor(v, 32);           // sum over lg: wave-partial per batch row lr
    if (lg == 0) red[w][lr] = v;
    __syncthreads();
    if (tid < BTILE) {
        float s = b_fc[0];
#pragma unroll
        for (int ww = 0; ww < NW; ++ww) s += red[ww][tid];
        out[B0 + tid] = s;
    }
}

extern "C" void kernel_launch(void* const* d_in, const int* in_sizes, int n_in,
                              void* d_out, int out_size, void* d_ws, size_t ws_size,
                              hipStream_t stream) {
    const float* x    = (const float*)d_in[0];
    const float* W_ih = (const float*)d_in[1];
    const float* W_hh = (const float*)d_in[2];
    const float* b_ih = (const float*)d_in[3];
    const float* b_hh = (const float*)d_in[4];
    const float* W_fc = (const float*)d_in[5];
    const float* b_fc = (const float*)d_in[6];
    float* out = (float*)d_out;

    const int B = in_sizes[0] / (TSZ * ISZ);  // 4096
    lstm_w16d<<<B / BTILE, NW * 64, 0, stream>>>(x, W_ih, W_hh, b_ih, b_hh, W_fc, b_fc, out);
}

// Round 16
// 265.534 us; speedup vs baseline: 1.9416x; 1.9416x over previous
//
#include <hip/hip_runtime.h>

#define HSZ 64
#define ISZ 8
#define TSZ 512
#define BTILE 16   // batch rows per block
#define NW 16      // waves per block (1024 threads) -> 4 waves/SIMD
#define KP 104     // k per row: [0,64) h | [64,72) x | [72,96) zero (b2 pad) | tail

typedef _Float16 f16;
typedef __attribute__((ext_vector_type(8))) _Float16 f16x8;
typedef __attribute__((ext_vector_type(4))) float f32x4;
typedef unsigned short u16;

__device__ __forceinline__ u16 f16bits(float f) {
    union { f16 h; u16 u; } v; v.h = (f16)f;
    return v.u;
}

// r9 structure (best measured: 253.7us) + serial-chain micro-cuts:
//  - dual accumulators: x-MFMA (bias C-in) runs independent of the 2-chained
//    h-MFMAs; combined with 4 v_add_f32 -> MFMA dep chain 3->2 deep, and the
//    x-MFMA can execute during b0/b1 ds_read latency.
// Operand-swapped MFMA: A = weights (M = 16 gate rows, gc = gate*64+4w+(lr>>2)),
// B = h/x (LDS), N = 16 batch. Lane (lr,lg) holds all 4 gates of unit
// (batch lr, hidden 4w+lg) in acc[0..3] -> act fully lane-local, no shuffles.
// Weights pre-scaled by -log2e (i,f,o) / -2log2e (g) so act uses exp2 directly;
// act = common-denominator form, 5 exp2 + 2 rcp. Bias = C-in of the x-MFMA.
// x staged by wave w lanes 0-7 into its batch row (LDS broadcast; global L1
// duplication measured 2x worse in r15). One __syncthreads per step.
__global__ __launch_bounds__(1024, 4) void lstm_w16e(
    const float* __restrict__ x,      // [B, T, I]
    const float* __restrict__ W_ih,   // [4H, I]
    const float* __restrict__ W_hh,   // [4H, H]
    const float* __restrict__ b_ih,   // [4H]
    const float* __restrict__ b_hh,   // [4H]
    const float* __restrict__ W_fc,   // [O, H]
    const float* __restrict__ b_fc,   // [O]
    float* __restrict__ out)          // [B, O]
{
    const int tid = threadIdx.x;
    const int w  = tid >> 6;          // wave 0..15, owns hidden units [4w, 4w+4)
    const int l  = tid & 63;
    const int lr = l & 15;            // A: M-row sel / B,C: batch col
    const int lg = l >> 4;            // k-group; act: hidden unit 4w+lg
    const int B0 = blockIdx.x * BTILE;
    const int hcol = 4 * w + lg;      // this lane's hidden unit

    __shared__ __align__(16) u16 H[2][BTILE][KP];  // [buf][batch row][k]
    __shared__ float red[NW][BTILE];

    for (int i = tid; i < 2 * BTILE * KP; i += 1024)
        ((u16*)H)[i] = 0;

    // ---- A-fragments (weights), pre-scaled; bias as C-in ----
    const int gate = lr & 3;
    const int gc   = gate * HSZ + 4 * w + (lr >> 2);   // gate row in [0,256)
    const float sc = (gate == 2) ? -2.885390082f : -1.442695041f;
    f16x8 wa0, wa1, wa2;
    {
        const float4 a = *reinterpret_cast<const float4*>(&W_hh[gc * HSZ + lg * 8]);
        const float4 b = *reinterpret_cast<const float4*>(&W_hh[gc * HSZ + lg * 8 + 4]);
        wa0[0] = (f16)(sc * a.x); wa0[1] = (f16)(sc * a.y);
        wa0[2] = (f16)(sc * a.z); wa0[3] = (f16)(sc * a.w);
        wa0[4] = (f16)(sc * b.x); wa0[5] = (f16)(sc * b.y);
        wa0[6] = (f16)(sc * b.z); wa0[7] = (f16)(sc * b.w);
    }
    {
        const float4 a = *reinterpret_cast<const float4*>(&W_hh[gc * HSZ + 32 + lg * 8]);
        const float4 b = *reinterpret_cast<const float4*>(&W_hh[gc * HSZ + 32 + lg * 8 + 4]);
        wa1[0] = (f16)(sc * a.x); wa1[1] = (f16)(sc * a.y);
        wa1[2] = (f16)(sc * a.z); wa1[3] = (f16)(sc * a.w);
        wa1[4] = (f16)(sc * b.x); wa1[5] = (f16)(sc * b.y);
        wa1[6] = (f16)(sc * b.z); wa1[7] = (f16)(sc * b.w);
    }
#pragma unroll
    for (int j = 0; j < 8; ++j) wa2[j] = (f16)0.0f;
    if (lg == 0) {                    // x-MFMA k-slice [64,72) = W_ih; rest zero
        const float4 a = *reinterpret_cast<const float4*>(&W_ih[gc * ISZ]);
        const float4 b = *reinterpret_cast<const float4*>(&W_ih[gc * ISZ + 4]);
        wa2[0] = (f16)(sc * a.x); wa2[1] = (f16)(sc * a.y);
        wa2[2] = (f16)(sc * a.z); wa2[3] = (f16)(sc * a.w);
        wa2[4] = (f16)(sc * b.x); wa2[5] = (f16)(sc * b.y);
        wa2[6] = (f16)(sc * b.z); wa2[7] = (f16)(sc * b.w);
    }

    // per-lane bias vector (C-in of the x-MFMA): gate r of unit hcol
    f32x4 bias4;
#pragma unroll
    for (int r = 0; r < 4; ++r) {
        const float s = (r == 2) ? -2.885390082f : -1.442695041f;
        bias4[r] = s * (b_ih[r * HSZ + hcol] + b_hh[r * HSZ + hcol]);
    }

    __syncthreads();  // zeroing visible

    // stage x(0) into buf 0: wave w covers batch row w, lanes 0..7
    const float* xptr = x + (size_t)(B0 + w) * TSZ * ISZ + l;   // valid for l<8
    if (l < 8)
        H[0][w][HSZ + l] = f16bits(xptr[0]);
    __syncthreads();

    // hoisted LDS offsets (u16 units)
    const u16* rd0 = &H[0][lr][lg * 8];
    const u16* rd1 = &H[1][lr][lg * 8];
    u16* wr0 = &H[0][lr][hcol];
    u16* wr1 = &H[1][lr][hcol];
    u16* xs0 = &H[0][w][HSZ + l];     // used by l<8 only
    u16* xs1 = &H[1][w][HSZ + l];

    float c = 0.0f, h = 0.0f;
    const float L2 = 2.885390082f;
    const f32x4 zero4 = {0.f, 0.f, 0.f, 0.f};

#define STEP(RD, WR, XS, XIDX, XGUARD)                                           \
    {                                                                            \
        float xv = 0.0f;                                                         \
        if ((l < 8) && (XGUARD))                                                 \
            xv = xptr[(size_t)(XIDX) * ISZ];                                     \
        const f16x8 b2 = *reinterpret_cast<const f16x8*>(RD + 64);               \
        f32x4 acc_x = __builtin_amdgcn_mfma_f32_16x16x32_f16(wa2, b2, bias4, 0, 0, 0); \
        const f16x8 b0 = *reinterpret_cast<const f16x8*>(RD);                    \
        const f16x8 b1 = *reinterpret_cast<const f16x8*>(RD + 32);               \
        f32x4 acc_h = __builtin_amdgcn_mfma_f32_16x16x32_f16(wa0, b0, zero4, 0, 0, 0); \
        acc_h = __builtin_amdgcn_mfma_f32_16x16x32_f16(wa1, b1, acc_h, 0, 0, 0); \
        const float p0 = acc_x[0] + acc_h[0];                                    \
        const float p1 = acc_x[1] + acc_h[1];                                    \
        const float p2 = acc_x[2] + acc_h[2];                                    \
        const float p3 = acc_x[3] + acc_h[3];                                    \
        const float ea = __builtin_amdgcn_exp2f(p0);                             \
        const float eb = __builtin_amdgcn_exp2f(p1);                             \
        const float ed = __builtin_amdgcn_exp2f(p2);                             \
        const float es = __builtin_amdgcn_exp2f(p3);                             \
        const float A1 = 1.0f + ea, B1 = 1.0f + eb, D1 = 1.0f + ed;              \
        const float R1 = __builtin_amdgcn_rcpf(A1 * B1 * D1);                    \
        c = fmaf(c * A1, D1, (1.0f - ed) * B1) * R1;                             \
        const float eu = __builtin_amdgcn_exp2f(-L2 * c);                        \
        const float R2 = __builtin_amdgcn_rcpf((1.0f + es) * (1.0f + eu));       \
        h = (1.0f - eu) * R2;                                                    \
        *(WR) = f16bits(h);                                                      \
        if ((l < 8) && (XGUARD))                                                 \
            *(XS) = f16bits(xv);                                                 \
        __syncthreads();                                                         \
    }

    for (int t = 0; t < TSZ; t += 2) {
        // step t: read buf0, write h/x into buf1. x(t+1) always exists.
        STEP(rd0, wr1, xs1, t + 1, true)
        // step t+1: read buf1, write into buf0. x(t+2) exists unless t == 510.
        STEP(rd1, wr0, xs0, t + 2, t < TSZ - 2)
    }
#undef STEP

    // ---- final FC: out[b] = sum_h h(b,hu) * W_fc[hu] + b_fc ----
    float v = h * W_fc[hcol];
    v += __shfl_xor(v, 16);
    v += __shfl_xor(v, 32);           // sum over lg: wave-partial per batch row lr
    if (lg == 0) red[w][lr] = v;
    __syncthreads();
    if (tid < BTILE) {
        float s = b_fc[0];
#pragma unroll
        for (int ww = 0; ww < NW; ++ww) s += red[ww][tid];
        out[B0 + tid] = s;
    }
}

extern "C" void kernel_launch(void* const* d_in, const int* in_sizes, int n_in,
                              void* d_out, int out_size, void* d_ws, size_t ws_size,
                              hipStream_t stream) {
    const float* x    = (const float*)d_in[0];
    const float* W_ih = (const float*)d_in[1];
    const float* W_hh = (const float*)d_in[2];
    const float* b_ih = (const float*)d_in[3];
    const float* b_hh = (const float*)d_in[4];
    const float* W_fc = (const float*)d_in[5];
    const float* b_fc = (const float*)d_in[6];
    float* out = (float*)d_out;

    const int B = in_sizes[0] / (TSZ * ISZ);  // 4096
    lstm_w16e<<<B / BTILE, NW * 64, 0, stream>>>(x, W_ih, W_hh, b_ih, b_hh, W_fc, b_fc, out);
}

// Round 17
// 253.373 us; speedup vs baseline: 2.0347x; 1.0480x over previous
//
#include <hip/hip_runtime.h>

#define HSZ 64
#define ISZ 8
#define TSZ 512
#define BTILE 16   // batch rows per block
#define NW 16      // waves per block (1024 threads) -> 4 waves/SIMD
#define KP 104     // k per row: [0,64) h | [64,72) x | [72,96) zero (read-only pad) | pad

typedef _Float16 f16;
typedef __attribute__((ext_vector_type(8))) _Float16 f16x8;
typedef __attribute__((ext_vector_type(4))) float f32x4;
typedef unsigned short u16;

__device__ __forceinline__ u16 f16bits(float f) {
    union { f16 h; u16 u; } v; v.h = (f16)f;
    return v.u;
}

// r9 kernel, verbatim (best measured: 253.7us across 16 structural variants).
// Operand-swapped MFMA LSTM:
//  - A = weights (M = 16 gate rows: gc(m)=(m&3)*64+4w+(m>>2)), held in VGPRs,
//    pre-scaled by -log2(e) (gates i,f,o) / -2log2(e) (gate g).
//  - B = h/x (N = 16 batch cols) from LDS, double-buffered, 3 ds_read_b128/wave.
//  - C layout: lane (lr,lg) holds all 4 gates of unit (batch lr, hidden 4w+lg)
//    in acc[0..3] -> activation fully lane-local (no shuffles).
//  - bias enters as the C-in of the x-MFMA (exact f32, pre-scaled).
//  - act: common-denominator form, 5 exp2 + 2 rcp per unit.
//  - 2x unrolled timestep loop: static double-buffer pointers, one
//    __syncthreads per step.
// Eliminated alternatives (measured): role-split +47%, reg-x +103%, raw asm
// barrier +79%, NW=8 geometry +13%, dual-block anti-phase +-0%, dual-acc +5%.
__global__ __launch_bounds__(1024, 4) void lstm_w16b(
    const float* __restrict__ x,      // [B, T, I]
    const float* __restrict__ W_ih,   // [4H, I]
    const float* __restrict__ W_hh,   // [4H, H]
    const float* __restrict__ b_ih,   // [4H]
    const float* __restrict__ b_hh,   // [4H]
    const float* __restrict__ W_fc,   // [O, H]
    const float* __restrict__ b_fc,   // [O]
    float* __restrict__ out)          // [B, O]
{
    const int tid = threadIdx.x;
    const int w  = tid >> 6;          // wave 0..15, owns hidden units [4w, 4w+4)
    const int l  = tid & 63;
    const int lr = l & 15;            // A: M-row sel / B,C: batch col
    const int lg = l >> 4;            // k-group; act: hidden unit 4w+lg
    const int B0 = blockIdx.x * BTILE;
    const int hcol = 4 * w + lg;      // this lane's hidden unit

    __shared__ __align__(16) u16 H[2][BTILE][KP];  // [buf][batch row][k]
    __shared__ float red[NW][BTILE];

    for (int i = tid; i < 2 * BTILE * KP; i += 1024)
        ((u16*)H)[i] = 0;

    // ---- A-fragments (weights, M-side) into registers, pre-scaled ----
    const int gate = lr & 3;
    const int gc   = gate * HSZ + 4 * w + (lr >> 2);   // gate row in [0,256)
    const float sc = (gate == 2) ? -2.885390082f : -1.442695041f;
    f16x8 wa0, wa1, wa2;
    {
        const float4 a = *reinterpret_cast<const float4*>(&W_hh[gc * HSZ + lg * 8]);
        const float4 b = *reinterpret_cast<const float4*>(&W_hh[gc * HSZ + lg * 8 + 4]);
        wa0[0] = (f16)(sc * a.x); wa0[1] = (f16)(sc * a.y);
        wa0[2] = (f16)(sc * a.z); wa0[3] = (f16)(sc * a.w);
        wa0[4] = (f16)(sc * b.x); wa0[5] = (f16)(sc * b.y);
        wa0[6] = (f16)(sc * b.z); wa0[7] = (f16)(sc * b.w);
    }
    {
        const float4 a = *reinterpret_cast<const float4*>(&W_hh[gc * HSZ + 32 + lg * 8]);
        const float4 b = *reinterpret_cast<const float4*>(&W_hh[gc * HSZ + 32 + lg * 8 + 4]);
        wa1[0] = (f16)(sc * a.x); wa1[1] = (f16)(sc * a.y);
        wa1[2] = (f16)(sc * a.z); wa1[3] = (f16)(sc * a.w);
        wa1[4] = (f16)(sc * b.x); wa1[5] = (f16)(sc * b.y);
        wa1[6] = (f16)(sc * b.z); wa1[7] = (f16)(sc * b.w);
    }
#pragma unroll
    for (int j = 0; j < 8; ++j) wa2[j] = (f16)0.0f;
    if (lg == 0) {                    // x-MFMA k-slice [64,72) = W_ih; rest zero
        const float4 a = *reinterpret_cast<const float4*>(&W_ih[gc * ISZ]);
        const float4 b = *reinterpret_cast<const float4*>(&W_ih[gc * ISZ + 4]);
        wa2[0] = (f16)(sc * a.x); wa2[1] = (f16)(sc * a.y);
        wa2[2] = (f16)(sc * a.z); wa2[3] = (f16)(sc * a.w);
        wa2[4] = (f16)(sc * b.x); wa2[5] = (f16)(sc * b.y);
        wa2[6] = (f16)(sc * b.z); wa2[7] = (f16)(sc * b.w);
    }

    // per-lane bias vector (C-in of the x-MFMA): gate r of unit hcol
    f32x4 bias4;
#pragma unroll
    for (int r = 0; r < 4; ++r) {
        const float s = (r == 2) ? -2.885390082f : -1.442695041f;
        bias4[r] = s * (b_ih[r * HSZ + hcol] + b_hh[r * HSZ + hcol]);
    }

    __syncthreads();  // zeroing visible

    // stage x(0) into buf 0: wave w covers batch row w, lanes 0..7
    const float* xptr = x + (size_t)(B0 + w) * TSZ * ISZ + l;   // valid for l<8
    if (l < 8)
        H[0][w][HSZ + l] = f16bits(xptr[0]);
    __syncthreads();

    // hoisted LDS offsets (u16 units)
    const u16* rd0 = &H[0][lr][lg * 8];
    const u16* rd1 = &H[1][lr][lg * 8];
    u16* wr0 = &H[0][lr][hcol];
    u16* wr1 = &H[1][lr][hcol];
    u16* xs0 = &H[0][w][HSZ + l];     // used by l<8 only
    u16* xs1 = &H[1][w][HSZ + l];

    float c = 0.0f, h = 0.0f;
    const float L2 = 2.885390082f;

#define STEP(RD, WR, XS, XIDX, XGUARD)                                           \
    {                                                                            \
        float xv = 0.0f;                                                         \
        if ((l < 8) && (XGUARD))                                                 \
            xv = xptr[(size_t)(XIDX) * ISZ];                                     \
        const f16x8 b0 = *reinterpret_cast<const f16x8*>(RD);                    \
        const f16x8 b1 = *reinterpret_cast<const f16x8*>(RD + 32);               \
        const f16x8 b2 = *reinterpret_cast<const f16x8*>(RD + 64);               \
        f32x4 acc = __builtin_amdgcn_mfma_f32_16x16x32_f16(wa2, b2, bias4, 0, 0, 0); \
        acc = __builtin_amdgcn_mfma_f32_16x16x32_f16(wa0, b0, acc, 0, 0, 0);     \
        acc = __builtin_amdgcn_mfma_f32_16x16x32_f16(wa1, b1, acc, 0, 0, 0);     \
        const float ea = __builtin_amdgcn_exp2f(acc[0]);                         \
        const float eb = __builtin_amdgcn_exp2f(acc[1]);                         \
        const float ed = __builtin_amdgcn_exp2f(acc[2]);                         \
        const float es = __builtin_amdgcn_exp2f(acc[3]);                         \
        const float A1 = 1.0f + ea, B1 = 1.0f + eb, D1 = 1.0f + ed;              \
        const float R1 = __builtin_amdgcn_rcpf(A1 * B1 * D1);                    \
        c = fmaf(c * A1, D1, (1.0f - ed) * B1) * R1;                             \
        const float eu = __builtin_amdgcn_exp2f(-L2 * c);                        \
        const float R2 = __builtin_amdgcn_rcpf((1.0f + es) * (1.0f + eu));       \
        h = (1.0f - eu) * R2;                                                    \
        *(WR) = f16bits(h);                                                      \
        if ((l < 8) && (XGUARD))                                                 \
            *(XS) = f16bits(xv);                                                 \
        __syncthreads();                                                         \
    }

    for (int t = 0; t < TSZ; t += 2) {
        // step t: read buf0, write h/x into buf1. x(t+1) always exists (t+1 odd <= 511).
        STEP(rd0, wr1, xs1, t + 1, true)
        // step t+1: read buf1, write into buf0. x(t+2) exists unless t == 510.
        STEP(rd1, wr0, xs0, t + 2, t < TSZ - 2)
    }
#undef STEP

    // ---- final FC: out[b] = sum_h h(b,hu) * W_fc[hu] + b_fc ----
    float v = h * W_fc[hcol];
    v += __shfl_xor(v, 16);
    v += __shfl_xor(v, 32);           // sum over lg: wave-partial per batch row lr
    if (lg == 0) red[w][lr] = v;
    __syncthreads();
    if (tid < BTILE) {
        float s = b_fc[0];
#pragma unroll
        for (int ww = 0; ww < NW; ++ww) s += red[ww][tid];
        out[B0 + tid] = s;
    }
}

extern "C" void kernel_launch(void* const* d_in, const int* in_sizes, int n_in,
                              void* d_out, int out_size, void* d_ws, size_t ws_size,
                              hipStream_t stream) {
    const float* x    = (const float*)d_in[0];
    const float* W_ih = (const float*)d_in[1];
    const float* W_hh = (const float*)d_in[2];
    const float* b_ih = (const float*)d_in[3];
    const float* b_hh = (const float*)d_in[4];
    const float* W_fc = (const float*)d_in[5];
    const float* b_fc = (const float*)d_in[6];
    float* out = (float*)d_out;

    const int B = in_sizes[0] / (TSZ * ISZ);  // 4096
    lstm_w16b<<<B / BTILE, NW * 64, 0, stream>>>(x, W_ih, W_hh, b_ih, b_hh, W_fc, b_fc, out);
}